// Round 4
// baseline (902.863 us; speedup 1.0000x reference)
//
#include <hip/hip_runtime.h>

// GCN layer, bucket-binned pull aggregation:
//   deg = bincount(row); dis = deg>0 ? rsqrt(deg) : 0
//   bucket b = row>>6 (64 rows/bucket); bcount[b] = sum of deg over bucket
//   bptr = scan(bcount); bin pass: binned[atomicAdd(cursor[b])] = (row,col)
//   z[n] = bf16( dis[n] * (x[n] @ W^T) )            [9.6 MB, halves gather traffic]
//   aggregate: one block per bucket, 12KB LDS fp32 tile, ds_add_f32 accumulation,
//              epilogue fuses out = relu(dis[row]*tile + bias)
// No per-row CSR, no fine 4B scatter (was 105MB line-amplified writes), no global
// float atomics.

#define NF 48
#define RB 64              // rows per bucket
#define CUR_STRIDE 16      // bucket cursor padding: 64B apart

__global__ void deg_kernel(const int* __restrict__ row, int* __restrict__ deg, int E) {
    int e = blockIdx.x * blockDim.x + threadIdx.x;
    if (e < E) atomicAdd(&deg[row[e]], 1);
}

__global__ void dis_kernel(const int* __restrict__ deg, float* __restrict__ dis, int N) {
    int i = blockIdx.x * blockDim.x + threadIdx.x;
    if (i < N) {
        int d = deg[i];
        dis[i] = (d > 0) ? rsqrtf((float)d) : 0.0f;
    }
}

// one wave per bucket: bcount[b] = sum deg[b*64 .. b*64+63]
__global__ void bcount_kernel(const int* __restrict__ deg, int* __restrict__ bcount, int N) {
    int b = blockIdx.x;
    int i = b * RB + threadIdx.x;        // blockDim.x == 64 == RB
    int v = (i < N) ? deg[i] : 0;
    #pragma unroll
    for (int off = 32; off >= 1; off >>= 1) v += __shfl_xor(v, off, 64);
    if (threadIdx.x == 0) bcount[b] = v;
}

// single-block exclusive scan of bcount[0..NB) -> bptr and (padded) bcursor
__global__ void scan_kernel(const int* __restrict__ bcount, int* __restrict__ bptr,
                            int* __restrict__ bcursor, int NB, int E) {
    __shared__ int wsum[8];
    __shared__ int carry_s;
    if (threadIdx.x == 0) carry_s = 0;
    __syncthreads();
    const int lane = threadIdx.x & 63;
    const int wave = threadIdx.x >> 6;
    const int nw = blockDim.x >> 6;      // 8
    for (int base = 0; base < NB; base += blockDim.x) {
        int i = base + threadIdx.x;
        int v = (i < NB) ? bcount[i] : 0;
        int incl = v;
        #pragma unroll
        for (int off = 1; off < 64; off <<= 1) {
            int t = __shfl_up(incl, off, 64);
            if (lane >= off) incl += t;
        }
        if (lane == 63) wsum[wave] = incl;
        __syncthreads();
        if (wave == 0 && lane < nw) {
            int wv = wsum[lane];
            int wi = wv;
            #pragma unroll
            for (int off = 1; off < 8; off <<= 1) {
                int t = __shfl_up(wi, off, 8);
                if ((lane & 7) >= off) wi += t;
            }
            wsum[lane] = wi - wv;
        }
        __syncthreads();
        if (i < NB) {
            int ex = carry_s + wsum[wave] + (incl - v);
            bptr[i] = ex;
            bcursor[i * CUR_STRIDE] = ex;
        }
        __syncthreads();
        if (threadIdx.x == blockDim.x - 1) carry_s += wsum[wave] + incl;
        __syncthreads();
    }
    if (threadIdx.x == 0) bptr[NB] = E;
}

__global__ void bin_kernel(const int* __restrict__ row, const int* __restrict__ col,
                           int* __restrict__ bcursor, uint2* __restrict__ binned, int E) {
    int e = blockIdx.x * blockDim.x + threadIdx.x;
    if (e >= E) return;
    int r = row[e];
    int c = col[e];
    int pos = atomicAdd(&bcursor[(r >> 6) * CUR_STRIDE], 1);
    binned[pos] = make_uint2((unsigned)r, (unsigned)c);
}

// z[n][f] = bf16( dis[n] * (x[n] @ W^T)[f] ); one thread per feature PAIR, uint store
__global__ void transform_kernel(const float* __restrict__ x, const float* __restrict__ W,
                                 const float* __restrict__ dis, unsigned* __restrict__ zp, int N) {
    __shared__ float Ws[NF * NF];
    for (int i = threadIdx.x; i < NF * NF; i += blockDim.x) Ws[i] = W[i];
    __syncthreads();
    int idx = blockIdx.x * blockDim.x + threadIdx.x;
    if (idx >= N * (NF / 2)) return;
    int n = idx / (NF / 2);
    int j = idx % (NF / 2);
    const float* xr = x + (size_t)n * NF;
    const float* w0 = Ws + (2 * j) * NF;
    const float* w1 = Ws + (2 * j + 1) * NF;
    float s0 = 0.0f, s1 = 0.0f;
#pragma unroll
    for (int k = 0; k < NF; k++) {
        float xv = xr[k];
        s0 = fmaf(xv, w0[k], s0);
        s1 = fmaf(xv, w1[k], s1);
    }
    float d = dis[n];
    s0 *= d; s1 *= d;
    unsigned u0 = __float_as_uint(s0);
    unsigned u1 = __float_as_uint(s1);
    u0 = (u0 + 0x7fffu + ((u0 >> 16) & 1u)) >> 16;   // RN to bf16
    u1 = (u1 + 0x7fffu + ((u1 >> 16) & 1u)) >> 16;
    zp[idx] = u0 | (u1 << 16);                        // feats 2j (lo), 2j+1 (hi)
}

// one block per bucket; 4 waves share the bucket's edge list; LDS fp32 tile.
__global__ void aggregate_kernel(const int* __restrict__ bptr, const uint2* __restrict__ binned,
                                 const unsigned short* __restrict__ z, const float* __restrict__ dis,
                                 const float* __restrict__ bias, float* __restrict__ out, int N) {
    __shared__ float tile[RB * NF];      // 12 KB
    for (int i = threadIdx.x; i < RB * NF; i += blockDim.x) tile[i] = 0.0f;
    __syncthreads();
    const int b = blockIdx.x;
    const int s = bptr[b];
    const int t = bptr[b + 1];
    const int lane = threadIdx.x & 63;
    const int wave = threadIdx.x >> 6;
    for (int base = s + wave * 64; base < t; base += 256) {
        int cnt = min(64, t - base);
        uint2 rc = (lane < cnt) ? binned[base + lane] : make_uint2(0u, 0u);
        int rv = (int)rc.x;
        int cv = (int)rc.y;
        int k = 0;
        for (; k + 2 <= cnt; k += 2) {
            int r0 = __shfl(rv, k, 64),     c0 = __shfl(cv, k, 64);
            int r1 = __shfl(rv, k + 1, 64), c1 = __shfl(cv, k + 1, 64);
            if (lane < NF) {
                unsigned a0 = z[(size_t)c0 * NF + lane];
                unsigned a1 = z[(size_t)c1 * NF + lane];
                atomicAdd(&tile[(r0 & (RB - 1)) * NF + lane], __uint_as_float(a0 << 16));
                atomicAdd(&tile[(r1 & (RB - 1)) * NF + lane], __uint_as_float(a1 << 16));
            }
        }
        if (k < cnt) {
            int r0 = __shfl(rv, k, 64), c0 = __shfl(cv, k, 64);
            if (lane < NF) {
                unsigned a0 = z[(size_t)c0 * NF + lane];
                atomicAdd(&tile[(r0 & (RB - 1)) * NF + lane], __uint_as_float(a0 << 16));
            }
        }
    }
    __syncthreads();
    const int r0n = b * RB;
    for (int e = threadIdx.x; e < RB * NF; e += blockDim.x) {
        int n = r0n + e / NF;
        int f = e % NF;
        if (n < N) {
            float v = dis[n] * tile[e] + bias[f];
            out[(size_t)n * NF + f] = v > 0.0f ? v : 0.0f;
        }
    }
}

extern "C" void kernel_launch(void* const* d_in, const int* in_sizes, int n_in,
                              void* d_out, int out_size, void* d_ws, size_t ws_size,
                              hipStream_t stream) {
    const float* x    = (const float*)d_in[0];
    const int*   ei   = (const int*)d_in[1];
    const float* W    = (const float*)d_in[2];
    const float* bias = (const float*)d_in[3];
    float* out = (float*)d_out;

    const int N = in_sizes[0] / NF;
    const int E = in_sizes[1] / 2;
    const int* row = ei;         // edge_index[0]
    const int* col = ei + E;     // edge_index[1]
    const int NB = (N + RB - 1) / RB;     // 1563 buckets

    // workspace layout
    char* ws = (char*)d_ws;
    unsigned* zp      = (unsigned*)ws;            ws += (size_t)N * NF * 2;          // 9.6 MB bf16
    uint2*    binned  = (uint2*)ws;               ws += (size_t)E * 8;               // 12.8 MB
    int*      deg     = (int*)ws;                 ws += (size_t)N * 4;
    float*    dis     = (float*)ws;               ws += (size_t)N * 4;
    int*      bcount  = (int*)ws;                 ws += (size_t)NB * 4;
    int*      bptr    = (int*)ws;                 ws += (size_t)(NB + 1) * 4;
    int*      bcursor = (int*)ws;                 ws += (size_t)NB * CUR_STRIDE * 4; // padded

    hipMemsetAsync(deg, 0, (size_t)N * 4, stream);

    deg_kernel<<<(E + 255) / 256, 256, 0, stream>>>(row, deg, E);
    dis_kernel<<<(N + 255) / 256, 256, 0, stream>>>(deg, dis, N);
    bcount_kernel<<<NB, 64, 0, stream>>>(deg, bcount, N);
    scan_kernel<<<1, 512, 0, stream>>>(bcount, bptr, bcursor, NB, E);
    bin_kernel<<<(E + 255) / 256, 256, 0, stream>>>(row, col, bcursor, binned, E);
    transform_kernel<<<(N * (NF / 2) + 255) / 256, 256, 0, stream>>>(x, W, dis, zp, N);
    aggregate_kernel<<<NB, 256, 0, stream>>>(bptr, binned, (const unsigned short*)zp, dis, bias, out, N);
}

// Round 5
// 399.335 us; speedup vs baseline: 2.2609x; 2.2609x over previous
//
#include <hip/hip_runtime.h>

// GCN layer, bucket-binned pull aggregation (register accumulate, NO float atomics,
// NO per-element LDS atomics):
//   deg = bincount(row); dis = deg>0 ? rsqrt(deg) : 0
//   zp[n] = packed bf16 pairs of dis[n] * (x[n] @ W^T)     [9.6 MB]
//   binning (bucket = row>>6, 64 rows):
//     A: per-chunk bucket histogram (LDS) -> blkhistT[bucket][chunk]
//     B1: exclusive scan over chunks per bucket (in place) + bucket totals
//     B2: exclusive scan of bucket totals -> bbase
//     C: scatter (row,col) to binned[bbase+blkoff+rank]  (contiguous per (chunk,bucket))
//   aggregate: one block per bucket; LDS counting-sort of cols by row (hist/cursor
//     atomics only ~2K/block); pull-gather with register accumulation:
//     half-wave 0 = even edges, half-wave 1 = odd edges, 24 lanes x uint (2 bf16 feats);
//     epilogue fuses dis[row]*acc + bias, ReLU, float2 stores.

#define NF 48
#define NPAIR 24           // NF/2 uints per node row in zp
#define RB 64              // rows per bucket
#define CHUNK 16384        // edges per binning chunk
#define SCOL_CAP 2048      // per-bucket LDS col capacity (mean 1024, +32 sigma)

__global__ void deg_kernel(const int* __restrict__ row, int* __restrict__ deg, int E) {
    int e = blockIdx.x * blockDim.x + threadIdx.x;
    if (e < E) atomicAdd(&deg[row[e]], 1);
}

__global__ void dis_kernel(const int* __restrict__ deg, float* __restrict__ dis, int N) {
    int i = blockIdx.x * blockDim.x + threadIdx.x;
    if (i < N) {
        int d = deg[i];
        dis[i] = (d > 0) ? rsqrtf((float)d) : 0.0f;
    }
}

// zp[n*24+j] = bf16(dis[n]*(x@W^T)[2j]) | bf16(...[2j+1])<<16
__global__ void transform_kernel(const float* __restrict__ x, const float* __restrict__ W,
                                 const float* __restrict__ dis, unsigned* __restrict__ zp, int N) {
    __shared__ float Ws[NF * NF];
    for (int i = threadIdx.x; i < NF * NF; i += blockDim.x) Ws[i] = W[i];
    __syncthreads();
    int idx = blockIdx.x * blockDim.x + threadIdx.x;
    if (idx >= N * NPAIR) return;
    int n = idx / NPAIR;
    int j = idx % NPAIR;
    const float* xr = x + (size_t)n * NF;
    const float* w0 = Ws + (2 * j) * NF;
    const float* w1 = Ws + (2 * j + 1) * NF;
    float s0 = 0.0f, s1 = 0.0f;
#pragma unroll
    for (int k = 0; k < NF; k++) {
        float xv = xr[k];
        s0 = fmaf(xv, w0[k], s0);
        s1 = fmaf(xv, w1[k], s1);
    }
    float d = dis[n];
    s0 *= d; s1 *= d;
    unsigned u0 = __float_as_uint(s0);
    unsigned u1 = __float_as_uint(s1);
    u0 = (u0 + 0x7fffu + ((u0 >> 16) & 1u)) >> 16;
    u1 = (u1 + 0x7fffu + ((u1 >> 16) & 1u)) >> 16;
    zp[idx] = u0 | (u1 << 16);
}

// Pass A: per-chunk bucket histogram
__global__ void histA_kernel(const int* __restrict__ row, int* __restrict__ blkhistT,
                             int NBUK, int NCH, int E) {
    extern __shared__ int hist[];       // NBUK ints
    for (int i = threadIdx.x; i < NBUK; i += blockDim.x) hist[i] = 0;
    __syncthreads();
    int b = blockIdx.x;
    int s = b * CHUNK, t = min(E, s + CHUNK);
    for (int e = s + threadIdx.x; e < t; e += blockDim.x)
        atomicAdd(&hist[row[e] >> 6], 1);
    __syncthreads();
    for (int k = threadIdx.x; k < NBUK; k += blockDim.x)
        blkhistT[(size_t)k * NCH + b] = hist[k];
}

// Pass B1: per bucket, exclusive scan over chunks (in place) + total
__global__ void scanB1_kernel(int* __restrict__ blkhistT, int* __restrict__ btotal, int NCH) {
    int k = blockIdx.x;
    int lane = threadIdx.x;             // blockDim.x == 64
    int* p = blkhistT + (size_t)k * NCH;
    int carry = 0;
    for (int base = 0; base < NCH; base += 64) {
        int i = base + lane;
        int v = (i < NCH) ? p[i] : 0;
        int incl = v;
        #pragma unroll
        for (int off = 1; off < 64; off <<= 1) {
            int u = __shfl_up(incl, off, 64);
            if (lane >= off) incl += u;
        }
        if (i < NCH) p[i] = carry + incl - v;
        carry += __shfl(incl, 63, 64);
    }
    if (lane == 0) btotal[k] = carry;
}

// Pass B2: single-block exclusive scan of bucket totals -> bbase
__global__ void scanB2_kernel(const int* __restrict__ btotal, int* __restrict__ bbase,
                              int NBUK, int E) {
    __shared__ int wsum[4];
    __shared__ int carry_s;
    if (threadIdx.x == 0) carry_s = 0;
    __syncthreads();
    const int lane = threadIdx.x & 63;
    const int wave = threadIdx.x >> 6;  // blockDim.x == 256
    for (int base = 0; base < NBUK; base += 256) {
        int i = base + threadIdx.x;
        int v = (i < NBUK) ? btotal[i] : 0;
        int incl = v;
        #pragma unroll
        for (int off = 1; off < 64; off <<= 1) {
            int u = __shfl_up(incl, off, 64);
            if (lane >= off) incl += u;
        }
        if (lane == 63) wsum[wave] = incl;
        __syncthreads();
        int woff = 0;
        #pragma unroll
        for (int w = 0; w < 4; w++) if (w < wave) woff += wsum[w];
        if (i < NBUK) bbase[i] = carry_s + woff + (incl - v);
        __syncthreads();
        if (threadIdx.x == 255) carry_s += woff + incl;
        __syncthreads();
    }
    if (threadIdx.x == 0) bbase[NBUK] = E;
}

// Pass C: scatter edges to bucket-grouped binned[]
__global__ void scatC_kernel(const int* __restrict__ row, const int* __restrict__ col,
                             const int* __restrict__ blkoffT, const int* __restrict__ bbase,
                             uint2* __restrict__ binned, int NBUK, int NCH, int E) {
    extern __shared__ int cur[];        // NBUK ints
    int b = blockIdx.x;
    for (int k = threadIdx.x; k < NBUK; k += blockDim.x)
        cur[k] = bbase[k] + blkoffT[(size_t)k * NCH + b];
    __syncthreads();
    int s = b * CHUNK, t = min(E, s + CHUNK);
    for (int e = s + threadIdx.x; e < t; e += blockDim.x) {
        int r = row[e];
        int c = col[e];
        int pos = atomicAdd(&cur[r >> 6], 1);
        binned[pos] = make_uint2((unsigned)r, (unsigned)c);
    }
}

// One block per bucket: LDS counting sort by row, then register-accumulate gather.
__global__ void aggregate_kernel(const int* __restrict__ bbase, const uint2* __restrict__ binned,
                                 const unsigned* __restrict__ zp, const float* __restrict__ dis,
                                 const float* __restrict__ bias, float* __restrict__ out, int N) {
    __shared__ int scol[SCOL_CAP];
    __shared__ int hist[RB];
    __shared__ int lrp[RB + 1];
    __shared__ int cur[RB];
    const int b = blockIdx.x;
    const int s = bbase[b];
    const int t = bbase[b + 1];
    const int cnt = t - s;
    const int tid = threadIdx.x;
    if (tid < RB) hist[tid] = 0;
    __syncthreads();
    for (int e = s + tid; e < t; e += 256)
        atomicAdd(&hist[binned[e].x & (RB - 1)], 1);
    __syncthreads();
    if (tid < RB) {                      // wave 0: 64-lane exclusive scan
        int v = hist[tid];
        int incl = v;
        #pragma unroll
        for (int off = 1; off < 64; off <<= 1) {
            int u = __shfl_up(incl, off, 64);
            if (tid >= off) incl += u;
        }
        lrp[tid] = incl - v;
        cur[tid] = incl - v;
        if (tid == RB - 1) lrp[RB] = incl;
    }
    __syncthreads();
    const bool sorted = (cnt <= SCOL_CAP);
    if (sorted) {
        for (int e = s + tid; e < t; e += 256) {
            uint2 rc = binned[e];
            int pos = atomicAdd(&cur[rc.x & (RB - 1)], 1);
            scol[pos] = (int)rc.y;
        }
    }
    __syncthreads();

    const int lane = tid & 63;
    const int wave = tid >> 6;
    const int h = lane >> 5;             // half-wave: edge parity
    const int j = lane & 31;             // feature-pair index
    const bool act = (j < NPAIR);
    float bb0 = 0.0f, bb1 = 0.0f;
    if (act) { bb0 = bias[2 * j]; bb1 = bias[2 * j + 1]; }
    const int rbase = b * RB;
    for (int ri = wave; ri < RB; ri += 4) {
        int r = rbase + ri;
        if (r >= N) break;
        float a0 = 0.0f, a1 = 0.0f;
        if (sorted) {
            int ks = lrp[ri], ke = lrp[ri + 1];
            int k = ks + h;
            for (; k + 2 < ke; k += 4) {     // unroll 2: edges k, k+2 of this parity
                int c0 = scol[k];
                int c1 = scol[k + 2];
                if (act) {
                    unsigned u0 = zp[(size_t)c0 * NPAIR + j];
                    unsigned u1 = zp[(size_t)c1 * NPAIR + j];
                    a0 += __uint_as_float(u0 << 16) + __uint_as_float(u1 << 16);
                    a1 += __uint_as_float(u0 & 0xffff0000u) + __uint_as_float(u1 & 0xffff0000u);
                }
            }
            for (; k < ke; k += 2) {
                int c0 = scol[k];
                if (act) {
                    unsigned u0 = zp[(size_t)c0 * NPAIR + j];
                    a0 += __uint_as_float(u0 << 16);
                    a1 += __uint_as_float(u0 & 0xffff0000u);
                }
            }
        } else {                         // overflow fallback (statistically unreachable)
            for (int e = s; e < t; e++) {
                uint2 rc = binned[e];
                if ((int)(rc.x & (RB - 1)) == ri && h == 0 && act) {
                    unsigned u0 = zp[(size_t)rc.y * NPAIR + j];
                    a0 += __uint_as_float(u0 << 16);
                    a1 += __uint_as_float(u0 & 0xffff0000u);
                }
            }
        }
        a0 += __shfl_xor(a0, 32, 64);    // combine edge parities
        a1 += __shfl_xor(a1, 32, 64);
        if (h == 0 && act) {
            float dr = dis[r];
            float v0 = dr * a0 + bb0;
            float v1 = dr * a1 + bb1;
            float2 o;
            o.x = v0 > 0.0f ? v0 : 0.0f;
            o.y = v1 > 0.0f ? v1 : 0.0f;
            *(float2*)(out + (size_t)r * NF + 2 * j) = o;
        }
    }
}

extern "C" void kernel_launch(void* const* d_in, const int* in_sizes, int n_in,
                              void* d_out, int out_size, void* d_ws, size_t ws_size,
                              hipStream_t stream) {
    const float* x    = (const float*)d_in[0];
    const int*   ei   = (const int*)d_in[1];
    const float* W    = (const float*)d_in[2];
    const float* bias = (const float*)d_in[3];
    float* out = (float*)d_out;

    const int N = in_sizes[0] / NF;
    const int E = in_sizes[1] / 2;
    const int* row = ei;                      // edge_index[0]
    const int* col = ei + E;                  // edge_index[1]
    const int NBUK = (N + RB - 1) / RB;       // 1563
    const int NCH  = (E + CHUNK - 1) / CHUNK; // 98

    // workspace layout
    char* ws = (char*)d_ws;
    unsigned* zp       = (unsigned*)ws;       ws += (size_t)N * NPAIR * 4;   // 9.6 MB
    uint2*    binned   = (uint2*)ws;          ws += (size_t)E * 8;           // 12.8 MB
    int*      deg      = (int*)ws;            ws += (size_t)N * 4;
    float*    dis      = (float*)ws;          ws += (size_t)N * 4;
    int*      blkhistT = (int*)ws;            ws += (size_t)NBUK * NCH * 4;  // 612 KB
    int*      btotal   = (int*)ws;            ws += (size_t)NBUK * 4;
    int*      bbase    = (int*)ws;            ws += (size_t)(NBUK + 1) * 4;

    hipMemsetAsync(deg, 0, (size_t)N * 4, stream);

    deg_kernel<<<(E + 255) / 256, 256, 0, stream>>>(row, deg, E);
    dis_kernel<<<(N + 255) / 256, 256, 0, stream>>>(deg, dis, N);
    transform_kernel<<<(N * NPAIR + 255) / 256, 256, 0, stream>>>(x, W, dis, zp, N);
    histA_kernel<<<NCH, 256, NBUK * 4, stream>>>(row, blkhistT, NBUK, NCH, E);
    scanB1_kernel<<<NBUK, 64, 0, stream>>>(blkhistT, btotal, NCH);
    scanB2_kernel<<<1, 256, 0, stream>>>(btotal, bbase, NBUK, E);
    scatC_kernel<<<NCH, 256, NBUK * 4, stream>>>(row, col, blkhistT, bbase, binned, NBUK, NCH, E);
    aggregate_kernel<<<NBUK, 256, 0, stream>>>(bbase, binned, zp, dis, bias, out, N);
}

// Round 6
// 277.168 us; speedup vs baseline: 3.2575x; 1.4408x over previous
//
#include <hip/hip_runtime.h>

// GCN layer, bucket-binned pull aggregation (register accumulate, no float atomics):
//   deg = bincount(row); dis = deg>0 ? rsqrt(deg) : 0
//   zp[n] = packed bf16 pairs of dis[n] * (x[n] @ W^T)     [9.6 MB]
//   binning (bucket = row>>6): 3-pass chunked counting sort -> binned[] packed as
//     (row&63)<<26 | col   (col < 2^17 fits)
//   aggregate: one block per bucket; LDS counting-sort by row (int atomics only);
//     pull-gather, register accumulation, fused dis*acc+bias+ReLU epilogue.
// R6 fixes: Ws LDS stride 48->49 (was 24-way bank conflict, 8.2e7 conflict cycles,
//   156us); binned packed uint2->uint (halves scatter/gather index traffic).

#define NF 48
#define NPAIR 24           // NF/2 uints per node row in zp
#define WS_LD 49           // padded leading dim for W in LDS (bank-conflict fix)
#define RB 64              // rows per bucket
#define CHUNK 16384        // edges per binning chunk
#define SCOL_CAP 2048      // per-bucket LDS col capacity (mean 1024, +32 sigma)

__global__ void deg_kernel(const int* __restrict__ row, int* __restrict__ deg, int E) {
    int e = blockIdx.x * blockDim.x + threadIdx.x;
    if (e < E) atomicAdd(&deg[row[e]], 1);
}

__global__ void dis_kernel(const int* __restrict__ deg, float* __restrict__ dis, int N) {
    int i = blockIdx.x * blockDim.x + threadIdx.x;
    if (i < N) {
        int d = deg[i];
        dis[i] = (d > 0) ? rsqrtf((float)d) : 0.0f;
    }
}

// zp[n*24+j] = bf16(dis[n]*(x@W^T)[2j]) | bf16(...[2j+1])<<16
__global__ void transform_kernel(const float* __restrict__ x, const float* __restrict__ W,
                                 const float* __restrict__ dis, unsigned* __restrict__ zp, int N) {
    __shared__ float Ws[NF * WS_LD];
    for (int i = threadIdx.x; i < NF * NF; i += blockDim.x)
        Ws[(i / NF) * WS_LD + (i % NF)] = W[i];
    __syncthreads();
    int idx = blockIdx.x * blockDim.x + threadIdx.x;
    if (idx >= N * NPAIR) return;
    int n = idx / NPAIR;
    int j = idx % NPAIR;
    const float* xr = x + (size_t)n * NF;
    const float* w0 = Ws + (2 * j) * WS_LD;
    const float* w1 = Ws + (2 * j + 1) * WS_LD;
    float s0 = 0.0f, s1 = 0.0f;
#pragma unroll
    for (int k = 0; k < NF; k++) {
        float xv = xr[k];
        s0 = fmaf(xv, w0[k], s0);
        s1 = fmaf(xv, w1[k], s1);
    }
    float d = dis[n];
    s0 *= d; s1 *= d;
    unsigned u0 = __float_as_uint(s0);
    unsigned u1 = __float_as_uint(s1);
    u0 = (u0 + 0x7fffu + ((u0 >> 16) & 1u)) >> 16;
    u1 = (u1 + 0x7fffu + ((u1 >> 16) & 1u)) >> 16;
    zp[idx] = u0 | (u1 << 16);
}

// Pass A: per-chunk bucket histogram
__global__ void histA_kernel(const int* __restrict__ row, int* __restrict__ blkhistT,
                             int NBUK, int NCH, int E) {
    extern __shared__ int hist[];       // NBUK ints
    for (int i = threadIdx.x; i < NBUK; i += blockDim.x) hist[i] = 0;
    __syncthreads();
    int b = blockIdx.x;
    int s = b * CHUNK, t = min(E, s + CHUNK);
    for (int e = s + threadIdx.x; e < t; e += blockDim.x)
        atomicAdd(&hist[row[e] >> 6], 1);
    __syncthreads();
    for (int k = threadIdx.x; k < NBUK; k += blockDim.x)
        blkhistT[(size_t)k * NCH + b] = hist[k];
}

// Pass B1: per bucket, exclusive scan over chunks (in place) + total
__global__ void scanB1_kernel(int* __restrict__ blkhistT, int* __restrict__ btotal, int NCH) {
    int k = blockIdx.x;
    int lane = threadIdx.x;             // blockDim.x == 64
    int* p = blkhistT + (size_t)k * NCH;
    int carry = 0;
    for (int base = 0; base < NCH; base += 64) {
        int i = base + lane;
        int v = (i < NCH) ? p[i] : 0;
        int incl = v;
        #pragma unroll
        for (int off = 1; off < 64; off <<= 1) {
            int u = __shfl_up(incl, off, 64);
            if (lane >= off) incl += u;
        }
        if (i < NCH) p[i] = carry + incl - v;
        carry += __shfl(incl, 63, 64);
    }
    if (lane == 0) btotal[k] = carry;
}

// Pass B2: single-block exclusive scan of bucket totals -> bbase
__global__ void scanB2_kernel(const int* __restrict__ btotal, int* __restrict__ bbase,
                              int NBUK, int E) {
    __shared__ int wsum[4];
    __shared__ int carry_s;
    if (threadIdx.x == 0) carry_s = 0;
    __syncthreads();
    const int lane = threadIdx.x & 63;
    const int wave = threadIdx.x >> 6;  // blockDim.x == 256
    for (int base = 0; base < NBUK; base += 256) {
        int i = base + threadIdx.x;
        int v = (i < NBUK) ? btotal[i] : 0;
        int incl = v;
        #pragma unroll
        for (int off = 1; off < 64; off <<= 1) {
            int u = __shfl_up(incl, off, 64);
            if (lane >= off) incl += u;
        }
        if (lane == 63) wsum[wave] = incl;
        __syncthreads();
        int woff = 0;
        #pragma unroll
        for (int w = 0; w < 4; w++) if (w < wave) woff += wsum[w];
        if (i < NBUK) bbase[i] = carry_s + woff + (incl - v);
        __syncthreads();
        if (threadIdx.x == 255) carry_s += woff + incl;
        __syncthreads();
    }
    if (threadIdx.x == 0) bbase[NBUK] = E;
}

// Pass C: scatter edges to bucket-grouped binned[], packed (row&63)<<26 | col
__global__ void scatC_kernel(const int* __restrict__ row, const int* __restrict__ col,
                             const int* __restrict__ blkoffT, const int* __restrict__ bbase,
                             unsigned* __restrict__ binned, int NBUK, int NCH, int E) {
    extern __shared__ int cur[];        // NBUK ints
    int b = blockIdx.x;
    for (int k = threadIdx.x; k < NBUK; k += blockDim.x)
        cur[k] = bbase[k] + blkoffT[(size_t)k * NCH + b];
    __syncthreads();
    int s = b * CHUNK, t = min(E, s + CHUNK);
    for (int e = s + threadIdx.x; e < t; e += blockDim.x) {
        int r = row[e];
        int c = col[e];
        int pos = atomicAdd(&cur[r >> 6], 1);
        binned[pos] = ((unsigned)(r & (RB - 1)) << 26) | (unsigned)c;
    }
}

// One block per bucket: LDS counting sort by row, then register-accumulate gather.
__global__ void aggregate_kernel(const int* __restrict__ bbase, const unsigned* __restrict__ binned,
                                 const unsigned* __restrict__ zp, const float* __restrict__ dis,
                                 const float* __restrict__ bias, float* __restrict__ out, int N) {
    __shared__ int scol[SCOL_CAP];
    __shared__ int hist[RB];
    __shared__ int lrp[RB + 1];
    __shared__ int cur[RB];
    const int b = blockIdx.x;
    const int s = bbase[b];
    const int t = bbase[b + 1];
    const int cnt = t - s;
    const int tid = threadIdx.x;
    if (tid < RB) hist[tid] = 0;
    __syncthreads();
    for (int e = s + tid; e < t; e += 256)
        atomicAdd(&hist[binned[e] >> 26], 1);
    __syncthreads();
    if (tid < RB) {                      // wave 0: 64-lane exclusive scan
        int v = hist[tid];
        int incl = v;
        #pragma unroll
        for (int off = 1; off < 64; off <<= 1) {
            int u = __shfl_up(incl, off, 64);
            if (tid >= off) incl += u;
        }
        lrp[tid] = incl - v;
        cur[tid] = incl - v;
        if (tid == RB - 1) lrp[RB] = incl;
    }
    __syncthreads();
    const bool sorted = (cnt <= SCOL_CAP);
    if (sorted) {
        for (int e = s + tid; e < t; e += 256) {
            unsigned rc = binned[e];
            int pos = atomicAdd(&cur[rc >> 26], 1);
            scol[pos] = (int)(rc & 0x3ffffffu);
        }
    }
    __syncthreads();

    const int lane = tid & 63;
    const int wave = tid >> 6;
    const int h = lane >> 5;             // half-wave: edge parity
    const int j = lane & 31;             // feature-pair index
    const bool act = (j < NPAIR);
    float bb0 = 0.0f, bb1 = 0.0f;
    if (act) { bb0 = bias[2 * j]; bb1 = bias[2 * j + 1]; }
    const int rbase = b * RB;
    for (int ri = wave; ri < RB; ri += 4) {
        int r = rbase + ri;
        if (r >= N) break;
        float a0 = 0.0f, a1 = 0.0f;
        if (sorted) {
            int ks = lrp[ri], ke = lrp[ri + 1];
            int k = ks + h;
            for (; k + 2 < ke; k += 4) {     // unroll 2: edges k, k+2 of this parity
                int c0 = scol[k];
                int c1 = scol[k + 2];
                if (act) {
                    unsigned u0 = zp[(size_t)c0 * NPAIR + j];
                    unsigned u1 = zp[(size_t)c1 * NPAIR + j];
                    a0 += __uint_as_float(u0 << 16) + __uint_as_float(u1 << 16);
                    a1 += __uint_as_float(u0 & 0xffff0000u) + __uint_as_float(u1 & 0xffff0000u);
                }
            }
            for (; k < ke; k += 2) {
                int c0 = scol[k];
                if (act) {
                    unsigned u0 = zp[(size_t)c0 * NPAIR + j];
                    a0 += __uint_as_float(u0 << 16);
                    a1 += __uint_as_float(u0 & 0xffff0000u);
                }
            }
        } else {                         // overflow fallback (statistically unreachable)
            for (int e = s; e < t; e++) {
                unsigned rc = binned[e];
                if ((int)(rc >> 26) == ri && h == 0 && act) {
                    unsigned u0 = zp[(size_t)(rc & 0x3ffffffu) * NPAIR + j];
                    a0 += __uint_as_float(u0 << 16);
                    a1 += __uint_as_float(u0 & 0xffff0000u);
                }
            }
        }
        a0 += __shfl_xor(a0, 32, 64);    // combine edge parities
        a1 += __shfl_xor(a1, 32, 64);
        if (h == 0 && act) {
            float dr = dis[r];
            float v0 = dr * a0 + bb0;
            float v1 = dr * a1 + bb1;
            float2 o;
            o.x = v0 > 0.0f ? v0 : 0.0f;
            o.y = v1 > 0.0f ? v1 : 0.0f;
            *(float2*)(out + (size_t)r * NF + 2 * j) = o;
        }
    }
}

extern "C" void kernel_launch(void* const* d_in, const int* in_sizes, int n_in,
                              void* d_out, int out_size, void* d_ws, size_t ws_size,
                              hipStream_t stream) {
    const float* x    = (const float*)d_in[0];
    const int*   ei   = (const int*)d_in[1];
    const float* W    = (const float*)d_in[2];
    const float* bias = (const float*)d_in[3];
    float* out = (float*)d_out;

    const int N = in_sizes[0] / NF;
    const int E = in_sizes[1] / 2;
    const int* row = ei;                      // edge_index[0]
    const int* col = ei + E;                  // edge_index[1]
    const int NBUK = (N + RB - 1) / RB;       // 1563
    const int NCH  = (E + CHUNK - 1) / CHUNK; // 98

    // workspace layout
    char* ws = (char*)d_ws;
    unsigned* zp       = (unsigned*)ws;       ws += (size_t)N * NPAIR * 4;   // 9.6 MB
    unsigned* binned   = (unsigned*)ws;       ws += (size_t)E * 4;           // 6.4 MB
    int*      deg      = (int*)ws;            ws += (size_t)N * 4;
    float*    dis      = (float*)ws;          ws += (size_t)N * 4;
    int*      blkhistT = (int*)ws;            ws += (size_t)NBUK * NCH * 4;  // 612 KB
    int*      btotal   = (int*)ws;            ws += (size_t)NBUK * 4;
    int*      bbase    = (int*)ws;            ws += (size_t)(NBUK + 1) * 4;

    hipMemsetAsync(deg, 0, (size_t)N * 4, stream);

    deg_kernel<<<(E + 255) / 256, 256, 0, stream>>>(row, deg, E);
    dis_kernel<<<(N + 255) / 256, 256, 0, stream>>>(deg, dis, N);
    transform_kernel<<<(N * NPAIR + 255) / 256, 256, 0, stream>>>(x, W, dis, zp, N);
    histA_kernel<<<NCH, 256, NBUK * 4, stream>>>(row, blkhistT, NBUK, NCH, E);
    scanB1_kernel<<<NBUK, 64, 0, stream>>>(blkhistT, btotal, NCH);
    scanB2_kernel<<<1, 256, 0, stream>>>(btotal, bbase, NBUK, E);
    scatC_kernel<<<NCH, 256, NBUK * 4, stream>>>(row, col, blkhistT, bbase, binned, NBUK, NCH, E);
    aggregate_kernel<<<NBUK, 256, 0, stream>>>(bbase, binned, zp, dis, bias, out, N);
}

// Round 7
// 212.296 us; speedup vs baseline: 4.2529x; 1.3056x over previous
//
#include <hip/hip_runtime.h>

// GCN layer, bucket-binned pull aggregation (register accumulate, no float atomics,
// no global int atomics):
//   binning (bucket = row>>6): 3-pass chunked counting sort -> binned[] packed as
//     (row&63)<<26 | col
//   degdis: one block per bucket, LDS histogram of row&63 -> deg; dis = rsqrt(deg);
//     also writes lrp[b][0..64] (exclusive scan of per-row counts) for aggregate.
//   zp[n] = packed bf16 pairs of dis[n] * (x[n] @ W^T)     [9.6 MB]
//   aggregate: one block per bucket; LDS counting-sort by row using precomputed lrp;
//     pull-gather, register accumulation, fused dis*acc+bias+ReLU epilogue.
// History: global atomics (R1 scatter 983us, R6 deg 66us) and LDS float atomics
// (R4, 499us) all dead ends; Ws stride 49 fixes 24-way bank conflict (R6).

#define NF 48
#define NPAIR 24           // NF/2 uints per node row in zp
#define WS_LD 49           // padded leading dim for W in LDS (bank-conflict fix)
#define RB 64              // rows per bucket
#define CHUNK 16384        // edges per binning chunk
#define SCOL_CAP 2048      // per-bucket LDS col capacity (mean 1024, +32 sigma)

// zp[n*24+j] = bf16(dis[n]*(x@W^T)[2j]) | bf16(...[2j+1])<<16
__global__ void transform_kernel(const float* __restrict__ x, const float* __restrict__ W,
                                 const float* __restrict__ dis, unsigned* __restrict__ zp, int N) {
    __shared__ float Ws[NF * WS_LD];
    for (int i = threadIdx.x; i < NF * NF; i += blockDim.x)
        Ws[(i / NF) * WS_LD + (i % NF)] = W[i];
    __syncthreads();
    int idx = blockIdx.x * blockDim.x + threadIdx.x;
    if (idx >= N * NPAIR) return;
    int n = idx / NPAIR;
    int j = idx % NPAIR;
    const float* xr = x + (size_t)n * NF;
    const float* w0 = Ws + (2 * j) * WS_LD;
    const float* w1 = Ws + (2 * j + 1) * WS_LD;
    float s0 = 0.0f, s1 = 0.0f;
#pragma unroll
    for (int k = 0; k < NF; k++) {
        float xv = xr[k];
        s0 = fmaf(xv, w0[k], s0);
        s1 = fmaf(xv, w1[k], s1);
    }
    float d = dis[n];
    s0 *= d; s1 *= d;
    unsigned u0 = __float_as_uint(s0);
    unsigned u1 = __float_as_uint(s1);
    u0 = (u0 + 0x7fffu + ((u0 >> 16) & 1u)) >> 16;
    u1 = (u1 + 0x7fffu + ((u1 >> 16) & 1u)) >> 16;
    zp[idx] = u0 | (u1 << 16);
}

// Pass A: per-chunk bucket histogram
__global__ void histA_kernel(const int* __restrict__ row, int* __restrict__ blkhistT,
                             int NBUK, int NCH, int E) {
    extern __shared__ int hist[];       // NBUK ints
    for (int i = threadIdx.x; i < NBUK; i += blockDim.x) hist[i] = 0;
    __syncthreads();
    int b = blockIdx.x;
    int s = b * CHUNK, t = min(E, s + CHUNK);
    for (int e = s + threadIdx.x; e < t; e += blockDim.x)
        atomicAdd(&hist[row[e] >> 6], 1);
    __syncthreads();
    for (int k = threadIdx.x; k < NBUK; k += blockDim.x)
        blkhistT[(size_t)k * NCH + b] = hist[k];
}

// Pass B1: per bucket, exclusive scan over chunks (in place) + total
__global__ void scanB1_kernel(int* __restrict__ blkhistT, int* __restrict__ btotal, int NCH) {
    int k = blockIdx.x;
    int lane = threadIdx.x;             // blockDim.x == 64
    int* p = blkhistT + (size_t)k * NCH;
    int carry = 0;
    for (int base = 0; base < NCH; base += 64) {
        int i = base + lane;
        int v = (i < NCH) ? p[i] : 0;
        int incl = v;
        #pragma unroll
        for (int off = 1; off < 64; off <<= 1) {
            int u = __shfl_up(incl, off, 64);
            if (lane >= off) incl += u;
        }
        if (i < NCH) p[i] = carry + incl - v;
        carry += __shfl(incl, 63, 64);
    }
    if (lane == 0) btotal[k] = carry;
}

// Pass B2: single-block exclusive scan of bucket totals -> bbase
__global__ void scanB2_kernel(const int* __restrict__ btotal, int* __restrict__ bbase,
                              int NBUK, int E) {
    __shared__ int wsum[4];
    __shared__ int carry_s;
    if (threadIdx.x == 0) carry_s = 0;
    __syncthreads();
    const int lane = threadIdx.x & 63;
    const int wave = threadIdx.x >> 6;  // blockDim.x == 256
    for (int base = 0; base < NBUK; base += 256) {
        int i = base + threadIdx.x;
        int v = (i < NBUK) ? btotal[i] : 0;
        int incl = v;
        #pragma unroll
        for (int off = 1; off < 64; off <<= 1) {
            int u = __shfl_up(incl, off, 64);
            if (lane >= off) incl += u;
        }
        if (lane == 63) wsum[wave] = incl;
        __syncthreads();
        int woff = 0;
        #pragma unroll
        for (int w = 0; w < 4; w++) if (w < wave) woff += wsum[w];
        if (i < NBUK) bbase[i] = carry_s + woff + (incl - v);
        __syncthreads();
        if (threadIdx.x == 255) carry_s += woff + incl;
        __syncthreads();
    }
    if (threadIdx.x == 0) bbase[NBUK] = E;
}

// Pass C: scatter edges to bucket-grouped binned[], packed (row&63)<<26 | col
__global__ void scatC_kernel(const int* __restrict__ row, const int* __restrict__ col,
                             const int* __restrict__ blkoffT, const int* __restrict__ bbase,
                             unsigned* __restrict__ binned, int NBUK, int NCH, int E) {
    extern __shared__ int cur[];        // NBUK ints
    int b = blockIdx.x;
    for (int k = threadIdx.x; k < NBUK; k += blockDim.x)
        cur[k] = bbase[k] + blkoffT[(size_t)k * NCH + b];
    __syncthreads();
    int s = b * CHUNK, t = min(E, s + CHUNK);
    for (int e = s + threadIdx.x; e < t; e += blockDim.x) {
        int r = row[e];
        int c = col[e];
        int pos = atomicAdd(&cur[r >> 6], 1);
        binned[pos] = ((unsigned)(r & (RB - 1)) << 26) | (unsigned)c;
    }
}

// One block per bucket: LDS histogram of row&63 -> dis + per-bucket row scan (lrp_g).
__global__ void degdis_kernel(const int* __restrict__ bbase, const unsigned* __restrict__ binned,
                              float* __restrict__ dis, int* __restrict__ lrp_g, int N) {
    __shared__ int hist[RB];
    const int b = blockIdx.x;
    const int s = bbase[b];
    const int t = bbase[b + 1];
    const int tid = threadIdx.x;
    if (tid < RB) hist[tid] = 0;
    __syncthreads();
    for (int e = s + tid; e < t; e += 256)
        atomicAdd(&hist[binned[e] >> 26], 1);
    __syncthreads();
    if (tid < RB) {                      // wave 0: 64-lane exclusive scan
        int v = hist[tid];
        int incl = v;
        #pragma unroll
        for (int off = 1; off < 64; off <<= 1) {
            int u = __shfl_up(incl, off, 64);
            if (tid >= off) incl += u;
        }
        int* lp = lrp_g + (size_t)b * (RB + 1);
        lp[tid] = incl - v;
        if (tid == RB - 1) lp[RB] = incl;
        int n = b * RB + tid;
        if (n < N) dis[n] = (v > 0) ? rsqrtf((float)v) : 0.0f;
    }
}

// One block per bucket: LDS counting sort by row (lrp precomputed), then
// register-accumulate gather.
__global__ void aggregate_kernel(const int* __restrict__ bbase, const unsigned* __restrict__ binned,
                                 const int* __restrict__ lrp_g,
                                 const unsigned* __restrict__ zp, const float* __restrict__ dis,
                                 const float* __restrict__ bias, float* __restrict__ out, int N) {
    __shared__ int scol[SCOL_CAP];
    __shared__ int lrp[RB + 1];
    __shared__ int cur[RB];
    const int b = blockIdx.x;
    const int s = bbase[b];
    const int t = bbase[b + 1];
    const int cnt = t - s;
    const int tid = threadIdx.x;
    if (tid < RB + 1) {
        int v = lrp_g[(size_t)b * (RB + 1) + tid];
        lrp[tid] = v;
        if (tid < RB) cur[tid] = v;
    }
    __syncthreads();
    const bool sorted = (cnt <= SCOL_CAP);
    if (sorted) {
        for (int e = s + tid; e < t; e += 256) {
            unsigned rc = binned[e];
            int pos = atomicAdd(&cur[rc >> 26], 1);
            scol[pos] = (int)(rc & 0x3ffffffu);
        }
    }
    __syncthreads();

    const int lane = tid & 63;
    const int wave = tid >> 6;
    const int h = lane >> 5;             // half-wave: edge parity
    const int j = lane & 31;             // feature-pair index
    const bool act = (j < NPAIR);
    float bb0 = 0.0f, bb1 = 0.0f;
    if (act) { bb0 = bias[2 * j]; bb1 = bias[2 * j + 1]; }
    const int rbase = b * RB;
    for (int ri = wave; ri < RB; ri += 4) {
        int r = rbase + ri;
        if (r >= N) break;
        float a0 = 0.0f, a1 = 0.0f;
        if (sorted) {
            int ks = lrp[ri], ke = lrp[ri + 1];
            int k = ks + h;
            for (; k + 2 < ke; k += 4) {     // unroll 2: edges k, k+2 of this parity
                int c0 = scol[k];
                int c1 = scol[k + 2];
                if (act) {
                    unsigned u0 = zp[(size_t)c0 * NPAIR + j];
                    unsigned u1 = zp[(size_t)c1 * NPAIR + j];
                    a0 += __uint_as_float(u0 << 16) + __uint_as_float(u1 << 16);
                    a1 += __uint_as_float(u0 & 0xffff0000u) + __uint_as_float(u1 & 0xffff0000u);
                }
            }
            for (; k < ke; k += 2) {
                int c0 = scol[k];
                if (act) {
                    unsigned u0 = zp[(size_t)c0 * NPAIR + j];
                    a0 += __uint_as_float(u0 << 16);
                    a1 += __uint_as_float(u0 & 0xffff0000u);
                }
            }
        } else {                         // overflow fallback (statistically unreachable)
            for (int e = s; e < t; e++) {
                unsigned rc = binned[e];
                if ((int)(rc >> 26) == ri && h == 0 && act) {
                    unsigned u0 = zp[(size_t)(rc & 0x3ffffffu) * NPAIR + j];
                    a0 += __uint_as_float(u0 << 16);
                    a1 += __uint_as_float(u0 & 0xffff0000u);
                }
            }
        }
        a0 += __shfl_xor(a0, 32, 64);    // combine edge parities
        a1 += __shfl_xor(a1, 32, 64);
        if (h == 0 && act) {
            float dr = dis[r];
            float v0 = dr * a0 + bb0;
            float v1 = dr * a1 + bb1;
            float2 o;
            o.x = v0 > 0.0f ? v0 : 0.0f;
            o.y = v1 > 0.0f ? v1 : 0.0f;
            *(float2*)(out + (size_t)r * NF + 2 * j) = o;
        }
    }
}

extern "C" void kernel_launch(void* const* d_in, const int* in_sizes, int n_in,
                              void* d_out, int out_size, void* d_ws, size_t ws_size,
                              hipStream_t stream) {
    const float* x    = (const float*)d_in[0];
    const int*   ei   = (const int*)d_in[1];
    const float* W    = (const float*)d_in[2];
    const float* bias = (const float*)d_in[3];
    float* out = (float*)d_out;

    const int N = in_sizes[0] / NF;
    const int E = in_sizes[1] / 2;
    const int* row = ei;                      // edge_index[0]
    const int* col = ei + E;                  // edge_index[1]
    const int NBUK = (N + RB - 1) / RB;       // 1563
    const int NCH  = (E + CHUNK - 1) / CHUNK; // 98

    // workspace layout
    char* ws = (char*)d_ws;
    unsigned* zp       = (unsigned*)ws;       ws += (size_t)N * NPAIR * 4;        // 9.6 MB
    unsigned* binned   = (unsigned*)ws;       ws += (size_t)E * 4;                // 6.4 MB
    float*    dis      = (float*)ws;          ws += (size_t)N * 4;
    int*      blkhistT = (int*)ws;            ws += (size_t)NBUK * NCH * 4;       // 612 KB
    int*      btotal   = (int*)ws;            ws += (size_t)NBUK * 4;
    int*      bbase    = (int*)ws;            ws += (size_t)(NBUK + 1) * 4;
    int*      lrp_g    = (int*)ws;            ws += (size_t)NBUK * (RB + 1) * 4;  // 406 KB

    histA_kernel<<<NCH, 256, NBUK * 4, stream>>>(row, blkhistT, NBUK, NCH, E);
    scanB1_kernel<<<NBUK, 64, 0, stream>>>(blkhistT, btotal, NCH);
    scanB2_kernel<<<1, 256, 0, stream>>>(btotal, bbase, NBUK, E);
    scatC_kernel<<<NCH, 256, NBUK * 4, stream>>>(row, col, blkhistT, bbase, binned, NBUK, NCH, E);
    degdis_kernel<<<NBUK, 256, 0, stream>>>(bbase, binned, dis, lrp_g, N);
    transform_kernel<<<(N * NPAIR + 255) / 256, 256, 0, stream>>>(x, W, dis, zp, N);
    aggregate_kernel<<<NBUK, 256, 0, stream>>>(bbase, binned, lrp_g, zp, dis, bias, out, N);
}

// Round 8
// 185.854 us; speedup vs baseline: 4.8579x; 1.1423x over previous
//
#include <hip/hip_runtime.h>

// GCN layer, bucket-binned pull aggregation (register accumulate, no float atomics,
// no global int atomics):
//   binning (bucket = row>>6): 3-pass chunked counting sort -> binned[] packed as
//     (row&63)<<26 | col; blkhist layout [chunk][bucket] (coalesced in histA/scatC,
//     strided only in tiny scanB1)
//   degdis: one block per bucket, LDS histogram -> dis + lrp (row scan) for aggregate
//   zp[n] = packed bf16 pairs of dis[n] * (x[n] @ W^T)     [9.6 MB]
//   aggregate: one block per bucket (512 thr); LDS counting-sort by row (lrp
//     precomputed); pull-gather unroll-4, fused dis*acc+bias+ReLU epilogue.
// History: global atomics (R1 983us, R6 66us) and LDS float atomics (R4 499us) are
// dead ends; Ws stride 49 fixes 24-way bank conflict (R6: 156->~15us).

#define NF 48
#define NPAIR 24           // NF/2 uints per node row in zp
#define WS_LD 49           // padded leading dim for W in LDS (bank-conflict fix)
#define RB 64              // rows per bucket
#define CHUNK 16384        // edges per binning chunk
#define SCOL_CAP 2048      // per-bucket LDS col capacity (mean 1024, +32 sigma)

// zp[n*24+j] = bf16(dis[n]*(x@W^T)[2j]) | bf16(...[2j+1])<<16
// block (24,8): j = threadIdx.x, n = blockIdx.x*8 + threadIdx.y (no div/mod)
__global__ void transform_kernel(const float* __restrict__ x, const float* __restrict__ W,
                                 const float* __restrict__ dis, unsigned* __restrict__ zp, int N) {
    __shared__ float Ws[NF * WS_LD];
    int tid = threadIdx.y * 24 + threadIdx.x;
    for (int i = tid; i < NF * NF; i += 192)
        Ws[(i / NF) * WS_LD + (i % NF)] = W[i];
    __syncthreads();
    int n = blockIdx.x * 8 + threadIdx.y;
    int j = threadIdx.x;
    if (n >= N) return;
    const float* xr = x + (size_t)n * NF;
    const float* w0 = Ws + (2 * j) * WS_LD;
    const float* w1 = Ws + (2 * j + 1) * WS_LD;
    float s0 = 0.0f, s1 = 0.0f;
#pragma unroll
    for (int k = 0; k < NF; k++) {
        float xv = xr[k];
        s0 = fmaf(xv, w0[k], s0);
        s1 = fmaf(xv, w1[k], s1);
    }
    float d = dis[n];
    s0 *= d; s1 *= d;
    unsigned u0 = __float_as_uint(s0);
    unsigned u1 = __float_as_uint(s1);
    u0 = (u0 + 0x7fffu + ((u0 >> 16) & 1u)) >> 16;
    u1 = (u1 + 0x7fffu + ((u1 >> 16) & 1u)) >> 16;
    zp[(size_t)n * NPAIR + j] = u0 | (u1 << 16);
}

// Pass A: per-chunk bucket histogram; blkhist[chunk][bucket] (coalesced store)
__global__ void histA_kernel(const int* __restrict__ row, int* __restrict__ blkhist,
                             int NBUK, int E) {
    extern __shared__ int hist[];       // NBUK ints
    for (int i = threadIdx.x; i < NBUK; i += blockDim.x) hist[i] = 0;
    __syncthreads();
    int b = blockIdx.x;
    int s = b * CHUNK, t = min(E, s + CHUNK);
    int nv = (t - s) >> 2;              // int4 groups
    const int4* r4 = (const int4*)(row + s);
    for (int i = threadIdx.x; i < nv; i += blockDim.x) {
        int4 r = r4[i];
        atomicAdd(&hist[r.x >> 6], 1);
        atomicAdd(&hist[r.y >> 6], 1);
        atomicAdd(&hist[r.z >> 6], 1);
        atomicAdd(&hist[r.w >> 6], 1);
    }
    for (int e = s + nv * 4 + threadIdx.x; e < t; e += blockDim.x)
        atomicAdd(&hist[row[e] >> 6], 1);
    __syncthreads();
    int* dst = blkhist + (size_t)b * NBUK;
    for (int k = threadIdx.x; k < NBUK; k += blockDim.x) dst[k] = hist[k];
}

// Pass B1: per bucket, exclusive scan over chunks (in place, strided) + total
__global__ void scanB1_kernel(int* __restrict__ blkhist, int* __restrict__ btotal,
                              int NBUK, int NCH) {
    int k = blockIdx.x;
    int lane = threadIdx.x;             // blockDim.x == 64
    int carry = 0;
    for (int base = 0; base < NCH; base += 64) {
        int i = base + lane;
        int v = (i < NCH) ? blkhist[(size_t)i * NBUK + k] : 0;
        int incl = v;
        #pragma unroll
        for (int off = 1; off < 64; off <<= 1) {
            int u = __shfl_up(incl, off, 64);
            if (lane >= off) incl += u;
        }
        if (i < NCH) blkhist[(size_t)i * NBUK + k] = carry + incl - v;
        carry += __shfl(incl, 63, 64);
    }
    if (lane == 0) btotal[k] = carry;
}

// Pass B2: single-block exclusive scan of bucket totals -> bbase
__global__ void scanB2_kernel(const int* __restrict__ btotal, int* __restrict__ bbase,
                              int NBUK, int E) {
    __shared__ int wsum[8];
    __shared__ int carry_s;
    if (threadIdx.x == 0) carry_s = 0;
    __syncthreads();
    const int lane = threadIdx.x & 63;
    const int wave = threadIdx.x >> 6;  // blockDim.x == 512
    for (int base = 0; base < NBUK; base += 512) {
        int i = base + threadIdx.x;
        int v = (i < NBUK) ? btotal[i] : 0;
        int incl = v;
        #pragma unroll
        for (int off = 1; off < 64; off <<= 1) {
            int u = __shfl_up(incl, off, 64);
            if (lane >= off) incl += u;
        }
        if (lane == 63) wsum[wave] = incl;
        __syncthreads();
        int woff = 0;
        #pragma unroll
        for (int w = 0; w < 8; w++) if (w < wave) woff += wsum[w];
        if (i < NBUK) bbase[i] = carry_s + woff + (incl - v);
        __syncthreads();
        if (threadIdx.x == 511) carry_s += woff + incl;
        __syncthreads();
    }
    if (threadIdx.x == 0) bbase[NBUK] = E;
}

// Pass C: scatter edges to bucket-grouped binned[], packed (row&63)<<26 | col
__global__ void scatC_kernel(const int* __restrict__ row, const int* __restrict__ col,
                             const int* __restrict__ blkhist, const int* __restrict__ bbase,
                             unsigned* __restrict__ binned, int NBUK, int E) {
    extern __shared__ int cur[];        // NBUK ints
    int b = blockIdx.x;
    const int* boff = blkhist + (size_t)b * NBUK;
    for (int k = threadIdx.x; k < NBUK; k += blockDim.x)
        cur[k] = bbase[k] + boff[k];    // coalesced
    __syncthreads();
    int s = b * CHUNK, t = min(E, s + CHUNK);
    int nv = (t - s) >> 2;
    const int4* r4 = (const int4*)(row + s);
    const int4* c4 = (const int4*)(col + s);
    for (int i = threadIdx.x; i < nv; i += blockDim.x) {
        int4 r = r4[i];
        int4 c = c4[i];
        int p0 = atomicAdd(&cur[r.x >> 6], 1);
        binned[p0] = ((unsigned)(r.x & (RB - 1)) << 26) | (unsigned)c.x;
        int p1 = atomicAdd(&cur[r.y >> 6], 1);
        binned[p1] = ((unsigned)(r.y & (RB - 1)) << 26) | (unsigned)c.y;
        int p2 = atomicAdd(&cur[r.z >> 6], 1);
        binned[p2] = ((unsigned)(r.z & (RB - 1)) << 26) | (unsigned)c.z;
        int p3 = atomicAdd(&cur[r.w >> 6], 1);
        binned[p3] = ((unsigned)(r.w & (RB - 1)) << 26) | (unsigned)c.w;
    }
    for (int e = s + nv * 4 + threadIdx.x; e < t; e += blockDim.x) {
        int r = row[e], c = col[e];
        int pos = atomicAdd(&cur[r >> 6], 1);
        binned[pos] = ((unsigned)(r & (RB - 1)) << 26) | (unsigned)c;
    }
}

// One block per bucket: LDS histogram of row&63 -> dis + per-bucket row scan (lrp_g).
__global__ void degdis_kernel(const int* __restrict__ bbase, const unsigned* __restrict__ binned,
                              float* __restrict__ dis, int* __restrict__ lrp_g, int N) {
    __shared__ int hist[RB];
    const int b = blockIdx.x;
    const int s = bbase[b];
    const int t = bbase[b + 1];
    const int tid = threadIdx.x;
    if (tid < RB) hist[tid] = 0;
    __syncthreads();
    for (int e = s + tid; e < t; e += 256)
        atomicAdd(&hist[binned[e] >> 26], 1);
    __syncthreads();
    if (tid < RB) {
        int v = hist[tid];
        int incl = v;
        #pragma unroll
        for (int off = 1; off < 64; off <<= 1) {
            int u = __shfl_up(incl, off, 64);
            if (tid >= off) incl += u;
        }
        int* lp = lrp_g + (size_t)b * (RB + 1);
        lp[tid] = incl - v;
        if (tid == RB - 1) lp[RB] = incl;
        int n = b * RB + tid;
        if (n < N) dis[n] = (v > 0) ? rsqrtf((float)v) : 0.0f;
    }
}

// One block (512 thr) per bucket: LDS counting sort by row, unroll-4 gather.
__global__ void aggregate_kernel(const int* __restrict__ bbase, const unsigned* __restrict__ binned,
                                 const int* __restrict__ lrp_g,
                                 const unsigned* __restrict__ zp, const float* __restrict__ dis,
                                 const float* __restrict__ bias, float* __restrict__ out, int N) {
    __shared__ int scol[SCOL_CAP];
    __shared__ int lrp[RB + 1];
    __shared__ int cur[RB];
    const int b = blockIdx.x;
    const int s = bbase[b];
    const int t = bbase[b + 1];
    const int cnt = t - s;
    const int tid = threadIdx.x;
    if (tid < RB + 1) {
        int v = lrp_g[(size_t)b * (RB + 1) + tid];
        lrp[tid] = v;
        if (tid < RB) cur[tid] = v;
    }
    __syncthreads();
    const bool sorted = (cnt <= SCOL_CAP);
    if (sorted) {
        for (int e = s + tid; e < t; e += 512) {
            unsigned rc = binned[e];
            int pos = atomicAdd(&cur[rc >> 26], 1);
            scol[pos] = (int)(rc & 0x3ffffffu);
        }
    }
    __syncthreads();

    const int lane = tid & 63;
    const int wave = tid >> 6;           // 0..7
    const int h = lane >> 5;             // half-wave: edge parity
    const int j = lane & 31;             // feature-pair index
    const bool act = (j < NPAIR);
    float bb0 = 0.0f, bb1 = 0.0f;
    if (act) { bb0 = bias[2 * j]; bb1 = bias[2 * j + 1]; }
    const int rbase = b * RB;
    for (int ri = wave; ri < RB; ri += 8) {
        int r = rbase + ri;
        if (r >= N) break;
        float a0 = 0.0f, a1 = 0.0f;
        if (sorted) {
            int ks = lrp[ri], ke = lrp[ri + 1];
            int k = ks + h;
            for (; k + 6 < ke; k += 8) {     // unroll 4: edges k,k+2,k+4,k+6 of parity
                int c0 = scol[k];
                int c1 = scol[k + 2];
                int c2 = scol[k + 4];
                int c3 = scol[k + 6];
                if (act) {
                    unsigned u0 = zp[(size_t)c0 * NPAIR + j];
                    unsigned u1 = zp[(size_t)c1 * NPAIR + j];
                    unsigned u2 = zp[(size_t)c2 * NPAIR + j];
                    unsigned u3 = zp[(size_t)c3 * NPAIR + j];
                    a0 += (__uint_as_float(u0 << 16) + __uint_as_float(u1 << 16)) +
                          (__uint_as_float(u2 << 16) + __uint_as_float(u3 << 16));
                    a1 += (__uint_as_float(u0 & 0xffff0000u) + __uint_as_float(u1 & 0xffff0000u)) +
                          (__uint_as_float(u2 & 0xffff0000u) + __uint_as_float(u3 & 0xffff0000u));
                }
            }
            for (; k < ke; k += 2) {
                int c0 = scol[k];
                if (act) {
                    unsigned u0 = zp[(size_t)c0 * NPAIR + j];
                    a0 += __uint_as_float(u0 << 16);
                    a1 += __uint_as_float(u0 & 0xffff0000u);
                }
            }
        } else {                         // overflow fallback (statistically unreachable)
            for (int e = s; e < t; e++) {
                unsigned rc = binned[e];
                if ((int)(rc >> 26) == ri && h == 0 && act) {
                    unsigned u0 = zp[(size_t)(rc & 0x3ffffffu) * NPAIR + j];
                    a0 += __uint_as_float(u0 << 16);
                    a1 += __uint_as_float(u0 & 0xffff0000u);
                }
            }
        }
        a0 += __shfl_xor(a0, 32, 64);    // combine edge parities
        a1 += __shfl_xor(a1, 32, 64);
        if (h == 0 && act) {
            float dr = dis[r];
            float v0 = dr * a0 + bb0;
            float v1 = dr * a1 + bb1;
            float2 o;
            o.x = v0 > 0.0f ? v0 : 0.0f;
            o.y = v1 > 0.0f ? v1 : 0.0f;
            *(float2*)(out + (size_t)r * NF + 2 * j) = o;
        }
    }
}

extern "C" void kernel_launch(void* const* d_in, const int* in_sizes, int n_in,
                              void* d_out, int out_size, void* d_ws, size_t ws_size,
                              hipStream_t stream) {
    const float* x    = (const float*)d_in[0];
    const int*   ei   = (const int*)d_in[1];
    const float* W    = (const float*)d_in[2];
    const float* bias = (const float*)d_in[3];
    float* out = (float*)d_out;

    const int N = in_sizes[0] / NF;
    const int E = in_sizes[1] / 2;
    const int* row = ei;                      // edge_index[0]
    const int* col = ei + E;                  // edge_index[1]
    const int NBUK = (N + RB - 1) / RB;       // 1563
    const int NCH  = (E + CHUNK - 1) / CHUNK; // 98

    // workspace layout
    char* ws = (char*)d_ws;
    unsigned* zp      = (unsigned*)ws;       ws += (size_t)N * NPAIR * 4;        // 9.6 MB
    unsigned* binned  = (unsigned*)ws;       ws += (size_t)E * 4;                // 6.4 MB
    float*    dis     = (float*)ws;          ws += (size_t)N * 4;
    int*      blkhist = (int*)ws;            ws += (size_t)NCH * NBUK * 4;       // 612 KB
    int*      btotal  = (int*)ws;            ws += (size_t)NBUK * 4;
    int*      bbase   = (int*)ws;            ws += (size_t)(NBUK + 1) * 4;
    int*      lrp_g   = (int*)ws;            ws += (size_t)NBUK * (RB + 1) * 4;  // 406 KB

    histA_kernel<<<NCH, 512, NBUK * 4, stream>>>(row, blkhist, NBUK, E);
    scanB1_kernel<<<NBUK, 64, 0, stream>>>(blkhist, btotal, NBUK, NCH);
    scanB2_kernel<<<1, 512, 0, stream>>>(btotal, bbase, NBUK, E);
    scatC_kernel<<<NCH, 512, NBUK * 4, stream>>>(row, col, blkhist, bbase, binned, NBUK, E);
    degdis_kernel<<<NBUK, 256, 0, stream>>>(bbase, binned, dis, lrp_g, N);
    dim3 tb(24, 8);
    transform_kernel<<<(N + 7) / 8, tb, 0, stream>>>(x, W, dis, zp, N);
    aggregate_kernel<<<NBUK, 512, 0, stream>>>(bbase, binned, lrp_g, zp, dis, bias, out, N);
}